// Round 4
// baseline (118.436 us; speedup 1.0000x reference)
//
#include <hip/hip_runtime.h>
#include <hip/hip_bf16.h>

// Problem constants: B=256, LATENT=256, N=64, EMB=64, NBOND=5
// Dtypes (established R2/R3): ALL float tensors fp32 (inputs AND output),
// nra int32. The "(bf16" in the test label is hard-coded template text.
#define HUGEF 1000.0f

typedef __hip_bfloat16 bf16;

__device__ __forceinline__ float b2f(bf16 x) { return __bfloat162float(x); }

// -------------------------------------------------------------------------
// Kernel 1: fused
//   h[b, atom, e]   = z[b,:] @ Wn[:, atom*64+e] + bn[atom*64+e]
//   a'[b, atom, f]  = sum_e h[b,atom,e] * W1a[e,f] + b1[f]   (b1 folded in)
//   c [b, atom, f]  = sum_e h[b,atom,e] * W1b[e,f]
// Block = (one atom) x (64-batch tile). a', c stored bf16 in ws (4 MB).
// -------------------------------------------------------------------------
__global__ __launch_bounds__(256) void k_hac(
    const float* __restrict__ z, const float* __restrict__ Wn,
    const float* __restrict__ bn, const float* __restrict__ W1,
    const float* __restrict__ b1, bf16* __restrict__ a_ws,
    bf16* __restrict__ c_ws)
{
    __shared__ float buf0[64][68];  // stage1: z-tile [m][k]   stage2: W1a[e][f]
    __shared__ float buf1[64][68];  // stage1: Wn-tile [k][n]  stage2: W1b[e][f]
    __shared__ float buf2[64][68];  //                         stage2: h [b_local][e]

    const int t = threadIdx.x;
    const int tx = t & 15, ty = t >> 4;
    const int atom = blockIdx.x;        // 0..63
    const int m0 = blockIdx.y * 64;     // batch tile base
    const int n0 = atom * 64;           // column base in the 4096-wide GEMM

    float acc[4][4] = {};
    for (int k0 = 0; k0 < 256; k0 += 64) {
        __syncthreads();
        #pragma unroll
        for (int r = 0; r < 4; ++r) {           // z[m0+m][k0+kk..kk+3] -> buf0[m][kk]
            int q = t + 256 * r;
            int m = q >> 4, kk = (q & 15) * 4;
            *(float4*)&buf0[m][kk] = *(const float4*)&z[(m0 + m) * 256 + k0 + kk];
        }
        #pragma unroll
        for (int r = 0; r < 4; ++r) {           // Wn[k0+k][n0+nn..] -> buf1[k][nn]
            int q = t + 256 * r;
            int k = q >> 4, nn = (q & 15) * 4;
            *(float4*)&buf1[k][nn] = *(const float4*)&Wn[(k0 + k) * 4096 + n0 + nn];
        }
        __syncthreads();
        for (int k = 0; k < 64; ++k) {
            float4 bv = *(const float4*)&buf1[k][tx * 4];   // 2-way, ~free
            float bb[4] = {bv.x, bv.y, bv.z, bv.w};
            float aa[4];
            #pragma unroll
            for (int i = 0; i < 4; ++i) aa[i] = buf0[ty * 4 + i][k];  // broadcast
            #pragma unroll
            for (int i = 0; i < 4; ++i)
                #pragma unroll
                for (int jj = 0; jj < 4; ++jj) acc[i][jj] += aa[i] * bb[jj];
        }
    }
    __syncthreads();  // done reading buf0/buf1; safe to overwrite

    // h tile (with bn bias) -> buf2; stage W1a/W1b -> buf0/buf1
    {
        float bnv[4];
        #pragma unroll
        for (int jj = 0; jj < 4; ++jj) bnv[jj] = bn[n0 + tx * 4 + jj];
        #pragma unroll
        for (int i = 0; i < 4; ++i)
            #pragma unroll
            for (int jj = 0; jj < 4; ++jj)
                buf2[ty * 4 + i][tx * 4 + jj] = acc[i][jj] + bnv[jj];
        #pragma unroll
        for (int r = 0; r < 4; ++r) {
            int q = t + 256 * r;                 // q-th float4 of the 64x64 half
            int e = q >> 4, ff = (q & 15) * 4;
            *(float4*)&buf0[e][ff] = *(const float4*)&W1[4 * q];         // W1a
            *(float4*)&buf1[e][ff] = *(const float4*)&W1[4096 + 4 * q];  // W1b
        }
    }
    __syncthreads();

    // stage 2: h(64x64) @ W1a and @ W1b
    float aacc[4][4] = {}, cacc[4][4] = {};
    const int b0 = ty * 4, f0 = tx * 4;
    for (int e = 0; e < 64; ++e) {
        float4 wa = *(const float4*)&buf0[e][f0];
        float4 wb = *(const float4*)&buf1[e][f0];
        float wav[4] = {wa.x, wa.y, wa.z, wa.w};
        float wbv[4] = {wb.x, wb.y, wb.z, wb.w};
        #pragma unroll
        for (int i = 0; i < 4; ++i) {
            float hv = buf2[b0 + i][e];          // broadcast
            #pragma unroll
            for (int jj = 0; jj < 4; ++jj) {
                aacc[i][jj] += hv * wav[jj];
                cacc[i][jj] += hv * wbv[jj];
            }
        }
    }
    float b1v[4];
    #pragma unroll
    for (int jj = 0; jj < 4; ++jj) b1v[jj] = b1[f0 + jj];
    #pragma unroll
    for (int i = 0; i < 4; ++i) {
        int bi = m0 + b0 + i;
        int idx = bi * 4096 + n0 + f0;           // [b][atom][f], f0 mult of 4
        ushort4 av, cv;
        av.x = __bfloat16_as_ushort(__float2bfloat16(aacc[i][0] + b1v[0]));
        av.y = __bfloat16_as_ushort(__float2bfloat16(aacc[i][1] + b1v[1]));
        av.z = __bfloat16_as_ushort(__float2bfloat16(aacc[i][2] + b1v[2]));
        av.w = __bfloat16_as_ushort(__float2bfloat16(aacc[i][3] + b1v[3]));
        cv.x = __bfloat16_as_ushort(__float2bfloat16(cacc[i][0]));
        cv.y = __bfloat16_as_ushort(__float2bfloat16(cacc[i][1]));
        cv.z = __bfloat16_as_ushort(__float2bfloat16(cacc[i][2]));
        cv.w = __bfloat16_as_ushort(__float2bfloat16(cacc[i][3]));
        *(ushort4*)&a_ws[idx] = av;              // 8B aligned stores
        *(ushort4*)&c_ws[idx] = cv;
    }
}

// -------------------------------------------------------------------------
// Kernel 2: pairwise expansion + W2 contraction + mask + symmetrize.
//   out[b,i,j,:] = masked ? fill
//     : 0.5 * sum_f (relu(a'_i+c_j) + relu(a'_j+c_i))[f] * W2[f,:] + b2
// OUTPUT IS FP32 (R3->R4 fix).
// -------------------------------------------------------------------------
__global__ __launch_bounds__(256) void k_pairs(
    const bf16* __restrict__ a_ws, const bf16* __restrict__ c_ws,
    const int* __restrict__ nra, const float* __restrict__ W2,
    const float* __restrict__ b2, float* __restrict__ out)
{
    __shared__ float as[64][68];
    __shared__ float cs[64][68];
    __shared__ float w2t[5][68];   // transposed: w2t[k][f]

    const int t = threadIdx.x;
    const int bid = blockIdx.x;
    const int b = bid >> 2;
    const int ic = bid & 3;        // i-chunk: rows [ic*16, ic*16+16)
    const int n = nra[b];

    #pragma unroll
    for (int r = 0; r < 4; ++r) {
        int q = t + 256 * r;                  // q-th ushort4 of 4096 bf16
        int atom = q >> 4, ff = (q & 15) * 4;
        ushort4 av = *(const ushort4*)&a_ws[b * 4096 + 4 * q];
        ushort4 cv = *(const ushort4*)&c_ws[b * 4096 + 4 * q];
        as[atom][ff + 0] = b2f(__ushort_as_bfloat16(av.x));
        as[atom][ff + 1] = b2f(__ushort_as_bfloat16(av.y));
        as[atom][ff + 2] = b2f(__ushort_as_bfloat16(av.z));
        as[atom][ff + 3] = b2f(__ushort_as_bfloat16(av.w));
        cs[atom][ff + 0] = b2f(__ushort_as_bfloat16(cv.x));
        cs[atom][ff + 1] = b2f(__ushort_as_bfloat16(cv.y));
        cs[atom][ff + 2] = b2f(__ushort_as_bfloat16(cv.z));
        cs[atom][ff + 3] = b2f(__ushort_as_bfloat16(cv.w));
    }
    if (t < 64) {  // 256-thread block: each t<64 loads all 5 k for f=t
        #pragma unroll
        for (int k = 0; k < 5; ++k) w2t[k][t] = W2[t * 5 + k];
    }
    float b2v[5];
    #pragma unroll
    for (int k = 0; k < 5; ++k) b2v[k] = b2[k];
    __syncthreads();

    const int j = t & 63;
    const int wq = t >> 6;  // wave id 0..3 (uniform within a wave)
    const float fillv[5] = {-HUGEF, -HUGEF, -HUGEF, -HUGEF, HUGEF};

    #pragma unroll 1
    for (int q = 0; q < 4; ++q) {
        const int i = ic * 16 + wq * 4 + q;  // wave-uniform
        float* op = out + ((b * 64 + i) * 64 + j) * 5;
        if (i >= n) {  // whole row padding -> fill (wave-uniform branch)
            #pragma unroll
            for (int k = 0; k < 5; ++k) op[k] = fillv[k];
            continue;
        }
        float acc[5] = {0.f, 0.f, 0.f, 0.f, 0.f};
        for (int f4 = 0; f4 < 64; f4 += 4) {
            float4 ai = *(const float4*)&as[i][f4];  // uniform -> broadcast
            float4 ci = *(const float4*)&cs[i][f4];  // uniform -> broadcast
            float4 aj = *(const float4*)&as[j][f4];  // per-lane row read
            float4 cj = *(const float4*)&cs[j][f4];  // per-lane row read
            float s0 = fmaxf(ai.x + cj.x, 0.f) + fmaxf(aj.x + ci.x, 0.f);
            float s1 = fmaxf(ai.y + cj.y, 0.f) + fmaxf(aj.y + ci.y, 0.f);
            float s2 = fmaxf(ai.z + cj.z, 0.f) + fmaxf(aj.z + ci.z, 0.f);
            float s3 = fmaxf(ai.w + cj.w, 0.f) + fmaxf(aj.w + ci.w, 0.f);
            #pragma unroll
            for (int k = 0; k < 5; ++k) {
                float4 w = *(const float4*)&w2t[k][f4];  // uniform -> broadcast
                acc[k] += s0 * w.x + s1 * w.y + s2 * w.z + s3 * w.w;
            }
        }
        const bool masked = (j == i) || (j >= n);
        #pragma unroll
        for (int k = 0; k < 5; ++k) {
            float v = masked ? fillv[k] : (0.5f * acc[k] + b2v[k]);
            op[k] = v;
        }
    }
}

extern "C" void kernel_launch(void* const* d_in, const int* in_sizes, int n_in,
                              void* d_out, int out_size, void* d_ws, size_t ws_size,
                              hipStream_t stream)
{
    const float* z  = (const float*)d_in[0];   // (256, 256) fp32
    const int*   nra = (const int*)d_in[1];    // (256,) int32
    const float* Wn = (const float*)d_in[2];   // (256, 4096) fp32
    const float* bn = (const float*)d_in[3];   // (4096,) fp32
    const float* W1 = (const float*)d_in[4];   // (128, 64) fp32
    const float* b1 = (const float*)d_in[5];   // (64,) fp32
    const float* W2 = (const float*)d_in[6];   // (64, 5) fp32
    const float* b2 = (const float*)d_in[7];   // (5,) fp32
    float* out = (float*)d_out;                // (256, 64, 64, 5) fp32

    bf16* a_ws = (bf16*)d_ws;                  // 256*4096 bf16 (a' = a + b1)
    bf16* c_ws = a_ws + 256 * 4096;            // 256*4096 bf16

    hipLaunchKernelGGL(k_hac, dim3(64, 4), dim3(256), 0, stream,
                       z, Wn, bn, W1, b1, a_ws, c_ws);
    hipLaunchKernelGGL(k_pairs, dim3(1024), dim3(256), 0, stream,
                       a_ws, c_ws, nra, W2, b2, out);
}

// Round 5
// 115.782 us; speedup vs baseline: 1.0229x; 1.0229x over previous
//
#include <hip/hip_runtime.h>
#include <hip/hip_bf16.h>

// Problem constants: B=256, LATENT=256, N=64, EMB=64, NBOND=5
// Dtypes (established R2-R4): ALL float tensors fp32 (inputs AND output),
// nra int32. Workspace a'/c kept bf16 (absmax contribution ~0.002, thr=20).
#define HUGEF 1000.0f

typedef __hip_bfloat16 bf16;

__device__ __forceinline__ float b2f(bf16 x) { return __bfloat162float(x); }

// -------------------------------------------------------------------------
// Kernel 1: fused  h = z@Wn + bn ;  a' = h@W1a + b1 ;  c = h@W1b
// Block = (one atom=64-col tile) x (64-batch tile), grid (64,4), 256 thr.
// R5: register prefetch pipeline for global staging; z-tile and h-tile
// stored TRANSPOSED so both inner-loop operands are per-lane b128 reads.
// -------------------------------------------------------------------------
__global__ __launch_bounds__(256) void k_hac(
    const float* __restrict__ z, const float* __restrict__ Wn,
    const float* __restrict__ bn, const float* __restrict__ W1,
    const float* __restrict__ b1, bf16* __restrict__ a_ws,
    bf16* __restrict__ c_ws)
{
    __shared__ __align__(16) float buf0[64][68];  // s1: zT[k][m]   s2: W1a[e][f]
    __shared__ __align__(16) float buf1[64][68];  // s1: Wn[k][n]   s2: W1b[e][f]
    __shared__ __align__(16) float buf2[64][68];  //                s2: hT[e][b]

    const int t = threadIdx.x;
    const int tx = t & 15, ty = t >> 4;
    const int atom = blockIdx.x;        // 0..63
    const int m0 = blockIdx.y * 64;     // batch tile base
    const int n0 = atom * 64;           // column base in the 4096-wide GEMM

    // ---- software pipeline: prefetch K-tile into registers ----
    float4 zr[4], wr[4];
    #pragma unroll
    for (int r = 0; r < 4; ++r) {
        int q = t + 256 * r;
        int m = q >> 4, kk = (q & 15) * 4;       // z slice
        zr[r] = *(const float4*)&z[(m0 + m) * 256 + 0 + kk];
        int k = q >> 4, nn = (q & 15) * 4;       // Wn slice
        wr[r] = *(const float4*)&Wn[(0 + k) * 4096 + n0 + nn];
    }

    float acc[4][4] = {};
    for (int k0 = 0; k0 < 256; k0 += 64) {
        __syncthreads();                          // prior compute reads done
        #pragma unroll
        for (int r = 0; r < 4; ++r) {             // regs -> LDS
            int q = t + 256 * r;
            int m = q >> 4, kk = (q & 15) * 4;
            buf0[kk + 0][m] = zr[r].x;            // transposed store
            buf0[kk + 1][m] = zr[r].y;
            buf0[kk + 2][m] = zr[r].z;
            buf0[kk + 3][m] = zr[r].w;
            int k = q >> 4, nn = (q & 15) * 4;
            *(float4*)&buf1[k][nn] = wr[r];
        }
        if (k0 + 64 < 256) {                      // prefetch next tile
            #pragma unroll
            for (int r = 0; r < 4; ++r) {
                int q = t + 256 * r;
                int m = q >> 4, kk = (q & 15) * 4;
                zr[r] = *(const float4*)&z[(m0 + m) * 256 + (k0 + 64) + kk];
                int k = q >> 4, nn = (q & 15) * 4;
                wr[r] = *(const float4*)&Wn[(k0 + 64 + k) * 4096 + n0 + nn];
            }
        }
        __syncthreads();
        #pragma unroll 4
        for (int k = 0; k < 64; ++k) {
            float4 av = *(const float4*)&buf0[k][ty * 4];   // per-lane b128
            float4 bv = *(const float4*)&buf1[k][tx * 4];   // per-lane b128
            float aa[4] = {av.x, av.y, av.z, av.w};
            float bb[4] = {bv.x, bv.y, bv.z, bv.w};
            #pragma unroll
            for (int i = 0; i < 4; ++i)
                #pragma unroll
                for (int jj = 0; jj < 4; ++jj) acc[i][jj] += aa[i] * bb[jj];
        }
    }
    __syncthreads();  // done reading buf0/buf1; safe to overwrite

    // hT[e][b] (with bn bias) -> buf2; stage W1a/W1b -> buf0/buf1
    {
        float bnv[4];
        #pragma unroll
        for (int jj = 0; jj < 4; ++jj) bnv[jj] = bn[n0 + tx * 4 + jj];
        #pragma unroll
        for (int i = 0; i < 4; ++i)
            #pragma unroll
            for (int jj = 0; jj < 4; ++jj)
                buf2[tx * 4 + jj][ty * 4 + i] = acc[i][jj] + bnv[jj];  // transposed
        #pragma unroll
        for (int r = 0; r < 4; ++r) {
            int q = t + 256 * r;                 // q-th float4 of the 64x64 half
            int e = q >> 4, ff = (q & 15) * 4;
            *(float4*)&buf0[e][ff] = *(const float4*)&W1[4 * q];         // W1a
            *(float4*)&buf1[e][ff] = *(const float4*)&W1[4096 + 4 * q];  // W1b
        }
    }
    __syncthreads();

    // stage 2: h(64x64) @ W1a and @ W1b ; h read as per-lane b128 from hT
    float aacc[4][4] = {}, cacc[4][4] = {};
    const int b0 = ty * 4, f0 = tx * 4;
    #pragma unroll 4
    for (int e = 0; e < 64; ++e) {
        float4 wa = *(const float4*)&buf0[e][f0];
        float4 wb = *(const float4*)&buf1[e][f0];
        float4 hv4 = *(const float4*)&buf2[e][b0];          // per-lane b128
        float wav[4] = {wa.x, wa.y, wa.z, wa.w};
        float wbv[4] = {wb.x, wb.y, wb.z, wb.w};
        float hv[4] = {hv4.x, hv4.y, hv4.z, hv4.w};
        #pragma unroll
        for (int i = 0; i < 4; ++i) {
            #pragma unroll
            for (int jj = 0; jj < 4; ++jj) {
                aacc[i][jj] += hv[i] * wav[jj];
                cacc[i][jj] += hv[i] * wbv[jj];
            }
        }
    }
    float b1v[4];
    #pragma unroll
    for (int jj = 0; jj < 4; ++jj) b1v[jj] = b1[f0 + jj];
    #pragma unroll
    for (int i = 0; i < 4; ++i) {
        int bi = m0 + b0 + i;
        int idx = bi * 4096 + n0 + f0;           // [b][atom][f], f0 mult of 4
        ushort4 av, cv;
        av.x = __bfloat16_as_ushort(__float2bfloat16(aacc[i][0] + b1v[0]));
        av.y = __bfloat16_as_ushort(__float2bfloat16(aacc[i][1] + b1v[1]));
        av.z = __bfloat16_as_ushort(__float2bfloat16(aacc[i][2] + b1v[2]));
        av.w = __bfloat16_as_ushort(__float2bfloat16(aacc[i][3] + b1v[3]));
        cv.x = __bfloat16_as_ushort(__float2bfloat16(cacc[i][0]));
        cv.y = __bfloat16_as_ushort(__float2bfloat16(cacc[i][1]));
        cv.z = __bfloat16_as_ushort(__float2bfloat16(cacc[i][2]));
        cv.w = __bfloat16_as_ushort(__float2bfloat16(cacc[i][3]));
        *(ushort4*)&a_ws[idx] = av;              // 8B aligned stores
        *(ushort4*)&c_ws[idx] = cv;
    }
}

// -------------------------------------------------------------------------
// Kernel 2: pairwise expansion + W2 contraction + mask + symmetrize.
//   out[b,i,j,:] = masked ? fill
//     : 0.5 * sum_f (relu(a'_i+c_j) + relu(a'_j+c_i))[f] * W2[f,:] + b2
// R5: 4-row register blocking — each wave computes its 4 rows in ONE f-pass,
// amortizing aj/cj per-lane reads and the 5 w2t reads across 4 rows.
// LDS/row/iter: 9 -> 3.75 b128; now VALU-bound.
// -------------------------------------------------------------------------
__global__ __launch_bounds__(256, 4) void k_pairs(
    const bf16* __restrict__ a_ws, const bf16* __restrict__ c_ws,
    const int* __restrict__ nra, const float* __restrict__ W2,
    const float* __restrict__ b2, float* __restrict__ out)
{
    __shared__ __align__(16) float as[64][68];
    __shared__ __align__(16) float cs[64][68];
    __shared__ __align__(16) float w2t[5][68];   // transposed: w2t[k][f]

    const int t = threadIdx.x;
    const int bid = blockIdx.x;
    const int b = bid >> 2;
    const int ic = bid & 3;        // i-chunk: rows [ic*16, ic*16+16)
    const int n = nra[b];

    #pragma unroll
    for (int r = 0; r < 4; ++r) {
        int q = t + 256 * r;                  // q-th ushort4 of 4096 bf16
        int atom = q >> 4, ff = (q & 15) * 4;
        ushort4 av = *(const ushort4*)&a_ws[b * 4096 + 4 * q];
        ushort4 cv = *(const ushort4*)&c_ws[b * 4096 + 4 * q];
        as[atom][ff + 0] = b2f(__ushort_as_bfloat16(av.x));
        as[atom][ff + 1] = b2f(__ushort_as_bfloat16(av.y));
        as[atom][ff + 2] = b2f(__ushort_as_bfloat16(av.z));
        as[atom][ff + 3] = b2f(__ushort_as_bfloat16(av.w));
        cs[atom][ff + 0] = b2f(__ushort_as_bfloat16(cv.x));
        cs[atom][ff + 1] = b2f(__ushort_as_bfloat16(cv.y));
        cs[atom][ff + 2] = b2f(__ushort_as_bfloat16(cv.z));
        cs[atom][ff + 3] = b2f(__ushort_as_bfloat16(cv.w));
    }
    if (t < 64) {  // each t<64 loads all 5 k for f=t
        #pragma unroll
        for (int k = 0; k < 5; ++k) w2t[k][t] = W2[t * 5 + k];
    }
    float b2v[5];
    #pragma unroll
    for (int k = 0; k < 5; ++k) b2v[k] = b2[k];
    __syncthreads();

    const int j = t & 63;
    const int wq = t >> 6;            // wave id 0..3
    const int i0 = ic * 16 + wq * 4;  // this wave's 4 rows (wave-uniform)
    const float fillv[5] = {-HUGEF, -HUGEF, -HUGEF, -HUGEF, HUGEF};

    if (i0 >= n) {  // all 4 rows padding -> fill fast path (wave-uniform)
        #pragma unroll
        for (int r = 0; r < 4; ++r) {
            float* op = out + ((b * 64 + i0 + r) * 64 + j) * 5;
            #pragma unroll
            for (int k = 0; k < 5; ++k) op[k] = fillv[k];
        }
        return;
    }

    float acc[4][5] = {};
    for (int f4 = 0; f4 < 64; f4 += 4) {
        float4 aj = *(const float4*)&as[j][f4];   // per-lane row read
        float4 cj = *(const float4*)&cs[j][f4];   // per-lane row read
        float4 w0 = *(const float4*)&w2t[0][f4];  // uniform -> broadcast
        float4 w1 = *(const float4*)&w2t[1][f4];
        float4 w2 = *(const float4*)&w2t[2][f4];
        float4 w3 = *(const float4*)&w2t[3][f4];
        float4 w4 = *(const float4*)&w2t[4][f4];
        #pragma unroll
        for (int r = 0; r < 4; ++r) {
            float4 ai = *(const float4*)&as[i0 + r][f4];  // uniform -> broadcast
            float4 ci = *(const float4*)&cs[i0 + r][f4];  // uniform -> broadcast
            float s0 = fmaxf(ai.x + cj.x, 0.f) + fmaxf(aj.x + ci.x, 0.f);
            float s1 = fmaxf(ai.y + cj.y, 0.f) + fmaxf(aj.y + ci.y, 0.f);
            float s2 = fmaxf(ai.z + cj.z, 0.f) + fmaxf(aj.z + ci.z, 0.f);
            float s3 = fmaxf(ai.w + cj.w, 0.f) + fmaxf(aj.w + ci.w, 0.f);
            acc[r][0] += s0 * w0.x + s1 * w0.y + s2 * w0.z + s3 * w0.w;
            acc[r][1] += s0 * w1.x + s1 * w1.y + s2 * w1.z + s3 * w1.w;
            acc[r][2] += s0 * w2.x + s1 * w2.y + s2 * w2.z + s3 * w2.w;
            acc[r][3] += s0 * w3.x + s1 * w3.y + s2 * w3.z + s3 * w3.w;
            acc[r][4] += s0 * w4.x + s1 * w4.y + s2 * w4.z + s3 * w4.w;
        }
    }

    #pragma unroll
    for (int r = 0; r < 4; ++r) {
        const int i = i0 + r;
        float* op = out + ((b * 64 + i) * 64 + j) * 5;
        if (i >= n) {  // row beyond n inside this wave's quad -> fill
            #pragma unroll
            for (int k = 0; k < 5; ++k) op[k] = fillv[k];
        } else {
            const bool masked = (j == i) || (j >= n);
            #pragma unroll
            for (int k = 0; k < 5; ++k)
                op[k] = masked ? fillv[k] : (0.5f * acc[r][k] + b2v[k]);
        }
    }
}

extern "C" void kernel_launch(void* const* d_in, const int* in_sizes, int n_in,
                              void* d_out, int out_size, void* d_ws, size_t ws_size,
                              hipStream_t stream)
{
    const float* z  = (const float*)d_in[0];   // (256, 256) fp32
    const int*   nra = (const int*)d_in[1];    // (256,) int32
    const float* Wn = (const float*)d_in[2];   // (256, 4096) fp32
    const float* bn = (const float*)d_in[3];   // (4096,) fp32
    const float* W1 = (const float*)d_in[4];   // (128, 64) fp32
    const float* b1 = (const float*)d_in[5];   // (64,) fp32
    const float* W2 = (const float*)d_in[6];   // (64, 5) fp32
    const float* b2 = (const float*)d_in[7];   // (5,) fp32
    float* out = (float*)d_out;                // (256, 64, 64, 5) fp32

    bf16* a_ws = (bf16*)d_ws;                  // 256*4096 bf16 (a' = a + b1)
    bf16* c_ws = a_ws + 256 * 4096;            // 256*4096 bf16

    hipLaunchKernelGGL(k_hac, dim3(64, 4), dim3(256), 0, stream,
                       z, Wn, bn, W1, b1, a_ws, c_ws);
    hipLaunchKernelGGL(k_pairs, dim3(1024), dim3(256), 0, stream,
                       a_ws, c_ws, nra, W2, b2, out);
}

// Round 6
// 110.039 us; speedup vs baseline: 1.0763x; 1.0522x over previous
//
#include <hip/hip_runtime.h>
#include <hip/hip_bf16.h>

// Problem constants: B=256, LATENT=256, N=64, EMB=64, NBOND=5
// Dtypes (established R2-R4): ALL float tensors fp32 (inputs AND output),
// nra int32. Threshold 20.0 -> bf16 internals are free precision-wise.
#define HUGEF 1000.0f

typedef __hip_bfloat16 bf16;
typedef __attribute__((ext_vector_type(8))) short short8;   // MFMA A/B frag (8 bf16)
typedef __attribute__((ext_vector_type(4))) float floatx4;  // MFMA C/D frag

__device__ __forceinline__ ushort f2bf(float x) {
    return __bfloat16_as_ushort(__float2bfloat16(x));
}
__device__ __forceinline__ float bflo(unsigned u) {  // low bf16 of packed word
    return __uint_as_float(u << 16);
}
__device__ __forceinline__ float bfhi(unsigned u) {  // high bf16 of packed word
    return __uint_as_float(u & 0xffff0000u);
}

// -------------------------------------------------------------------------
// Kernel 1 (R6: full MFMA):  h = z@Wn + bn ; a' = h@W1a + b1 ; c = h@W1b
// Block = (atom, 64-batch tile), grid (64,4), 256 thr = 4 waves.
// Stage 1: 64m x 64n tile, wave w owns rows [16w,16w+16), 4 n-tiles, K=256
//          in two 128-K LDS tiles. A-frag from zt[m][k] (bf16, k-contig);
//          B-frag from wnt[n][k] (transposed via coalesced k-strided gather).
// Stage 2: h -> ht LDS (bf16, +bn), W1a/W1b transposed to [f][e]; K=64.
// MFMA layouts (HW-verified, guide §3): A[m=lane&15][k=quad*8+j],
//   B[n=lane&15][k=quad*8+j] from [n][k] store, D[row=quad*4+r][col=lane&15].
// -------------------------------------------------------------------------
__global__ __launch_bounds__(256) void k_hac(
    const float* __restrict__ z, const float* __restrict__ Wn,
    const float* __restrict__ bn, const float* __restrict__ W1,
    const float* __restrict__ b1, bf16* __restrict__ a_ws,
    bf16* __restrict__ c_ws)
{
    __shared__ ushort zt[64][136];   // z-tile  [m][k0..127] bf16 (17.4 KB)
    __shared__ ushort wnt[64][136];  // Wn-tile [n][k0..127] bf16 (17.4 KB)
    __shared__ ushort ht[64][72];    // h       [m][e] bf16 (9.2 KB)
    __shared__ ushort w1at[64][72];  // W1a^T   [f][e] bf16
    __shared__ ushort w1bt[64][72];  // W1b^T   [f][e] bf16   total 61 KB

    const int t = threadIdx.x;
    const int lane = t & 63;
    const int wv = t >> 6;          // wave 0..3
    const int l15 = lane & 15;
    const int quad = lane >> 4;     // 0..3
    const int atom = blockIdx.x;
    const int m0 = blockIdx.y * 64;
    const int n0 = atom * 64;

    // ---- stage W1a/W1b transposed (independent of stage-1 LDS) ----
    {
        const int f = t & 63;
        const int g = t >> 6;
        #pragma unroll
        for (int qq = 0; qq < 4; ++qq) {
            int e = g * 16 + qq * 4;
            ushort4 va, vb;
            va.x = f2bf(W1[(e + 0) * 64 + f]);      // coalesced across f
            va.y = f2bf(W1[(e + 1) * 64 + f]);
            va.z = f2bf(W1[(e + 2) * 64 + f]);
            va.w = f2bf(W1[(e + 3) * 64 + f]);
            vb.x = f2bf(W1[(64 + e + 0) * 64 + f]);
            vb.y = f2bf(W1[(64 + e + 1) * 64 + f]);
            vb.z = f2bf(W1[(64 + e + 2) * 64 + f]);
            vb.w = f2bf(W1[(64 + e + 3) * 64 + f]);
            *(ushort4*)&w1at[f][e] = va;
            *(ushort4*)&w1bt[f][e] = vb;
        }
    }

    // ---- stage 1: z @ Wn over K=256 in two 128-wide LDS tiles ----
    floatx4 acc1[4] = {};
    for (int kt = 0; kt < 256; kt += 128) {
        __syncthreads();
        #pragma unroll
        for (int r = 0; r < 8; ++r) {             // zt[m][kk] <- z (coalesced f4)
            int q = t + 256 * r;
            int m = q >> 5, kk = (q & 31) * 4;
            float4 v = *(const float4*)&z[(m0 + m) * 256 + kt + kk];
            ushort4 u = {f2bf(v.x), f2bf(v.y), f2bf(v.z), f2bf(v.w)};
            *(ushort4*)&zt[m][kk] = u;
        }
        {                                          // wnt[n][k] <- Wn^T gather
            int n = t & 63, g = t >> 6;
            #pragma unroll
            for (int qq = 0; qq < 8; ++qq) {
                int k = g * 32 + qq * 4;
                const float* p = &Wn[(size_t)(kt + k) * 4096 + n0 + n];
                ushort4 u = {f2bf(p[0]), f2bf(p[4096]),
                             f2bf(p[2 * 4096]), f2bf(p[3 * 4096])};
                *(ushort4*)&wnt[n][k] = u;
            }
        }
        __syncthreads();
        #pragma unroll
        for (int ks = 0; ks < 4; ++ks) {           // 4 K=32 MFMA steps
            short8 a = *(const short8*)&zt[wv * 16 + l15][ks * 32 + quad * 8];
            #pragma unroll
            for (int nt = 0; nt < 4; ++nt) {
                short8 bf = *(const short8*)&wnt[nt * 16 + l15][ks * 32 + quad * 8];
                acc1[nt] = __builtin_amdgcn_mfma_f32_16x16x32_bf16(a, bf, acc1[nt], 0, 0, 0);
            }
        }
    }

    // ---- h (+bn) -> ht in A-operand-friendly [m][e] layout ----
    #pragma unroll
    for (int nt = 0; nt < 4; ++nt) {
        float bnv = bn[n0 + nt * 16 + l15];
        #pragma unroll
        for (int r = 0; r < 4; ++r)
            ht[wv * 16 + quad * 4 + r][nt * 16 + l15] = f2bf(acc1[nt][r] + bnv);
    }
    __syncthreads();

    // ---- stage 2: h @ W1a, h @ W1b (K=64, 2 MFMA steps) ----
    floatx4 acc2a[4] = {}, acc2c[4] = {};
    #pragma unroll
    for (int ks = 0; ks < 2; ++ks) {
        short8 a = *(const short8*)&ht[wv * 16 + l15][ks * 32 + quad * 8];
        #pragma unroll
        for (int ft = 0; ft < 4; ++ft) {
            short8 ba = *(const short8*)&w1at[ft * 16 + l15][ks * 32 + quad * 8];
            short8 bb = *(const short8*)&w1bt[ft * 16 + l15][ks * 32 + quad * 8];
            acc2a[ft] = __builtin_amdgcn_mfma_f32_16x16x32_bf16(a, ba, acc2a[ft], 0, 0, 0);
            acc2c[ft] = __builtin_amdgcn_mfma_f32_16x16x32_bf16(a, bb, acc2c[ft], 0, 0, 0);
        }
    }

    // ---- epilogue: a' = acc2a + b1 ; c = acc2c -> bf16 workspace ----
    #pragma unroll
    for (int ft = 0; ft < 4; ++ft) {
        float b1v = b1[ft * 16 + l15];
        #pragma unroll
        for (int r = 0; r < 4; ++r) {
            int m = wv * 16 + quad * 4 + r;
            size_t idx = (size_t)(m0 + m) * 4096 + n0 + ft * 16 + l15;
            a_ws[idx] = __float2bfloat16(acc2a[ft][r] + b1v);
            c_ws[idx] = __float2bfloat16(acc2c[ft][r]);
        }
    }
}

// -------------------------------------------------------------------------
// Kernel 2 (R6): pairwise relu + W2 contraction + mask + symmetrize.
// Grid 512 = (b, half): block owns rows [ic*32, ic*32+32), wave owns 8 rows.
// a'/c kept bf16x2-PACKED in LDS (same bits as ws -> zero extra error),
// halving a/c LDS instruction count; unpack = 1 shift/value.
// -------------------------------------------------------------------------
__global__ __launch_bounds__(256) void k_pairs(
    const bf16* __restrict__ a_ws, const bf16* __restrict__ c_ws,
    const int* __restrict__ nra, const float* __restrict__ W2,
    const float* __restrict__ b2, float* __restrict__ out)
{
    __shared__ unsigned ap[64][36];   // packed bf16x2: word w = f(2w), f(2w+1)
    __shared__ unsigned cp[64][36];
    __shared__ float w2t[5][68];      // w2t[k][f] fp32 (no unpack cost)

    const int t = threadIdx.x;
    const int b = blockIdx.x >> 1;
    const int ic = blockIdx.x & 1;
    const int n = nra[b];

    const ushort* ag = (const ushort*)a_ws + (size_t)b * 4096;
    const ushort* cg = (const ushort*)c_ws + (size_t)b * 4096;
    #pragma unroll
    for (int r = 0; r < 2; ++r) {
        int q = t + 256 * r;              // uint4 index 0..511
        int atom = q >> 3, wq = (q & 7) * 4;
        *(uint4*)&ap[atom][wq] = *(const uint4*)&ag[atom * 64 + wq * 2];
        *(uint4*)&cp[atom][wq] = *(const uint4*)&cg[atom * 64 + wq * 2];
    }
    if (t < 64) {
        #pragma unroll
        for (int k = 0; k < 5; ++k) w2t[k][t] = W2[t * 5 + k];
    }
    float b2v[5];
    #pragma unroll
    for (int k = 0; k < 5; ++k) b2v[k] = b2[k];
    __syncthreads();

    const int j = t & 63;
    const int wv = t >> 6;
    const int i0 = ic * 32 + wv * 8;     // this wave's 8 rows (uniform)
    const float fillv[5] = {-HUGEF, -HUGEF, -HUGEF, -HUGEF, HUGEF};

    if (i0 >= n) {                        // all 8 rows padding -> fill
        #pragma unroll
        for (int r = 0; r < 8; ++r) {
            float* op = out + ((size_t)(b * 64 + i0 + r) * 64 + j) * 5;
            #pragma unroll
            for (int k = 0; k < 5; ++k) op[k] = fillv[k];
        }
        return;
    }

    float acc[8][5] = {};
    for (int w8 = 0; w8 < 8; ++w8) {      // f-octet loop (8 f per iter)
        uint4 ajp = *(const uint4*)&ap[j][w8 * 4];   // per-lane row reads
        uint4 cjp = *(const uint4*)&cp[j][w8 * 4];
        float ajv[8], cjv[8];
        ajv[0] = bflo(ajp.x); ajv[1] = bfhi(ajp.x);
        ajv[2] = bflo(ajp.y); ajv[3] = bfhi(ajp.y);
        ajv[4] = bflo(ajp.z); ajv[5] = bfhi(ajp.z);
        ajv[6] = bflo(ajp.w); ajv[7] = bfhi(ajp.w);
        cjv[0] = bflo(cjp.x); cjv[1] = bfhi(cjp.x);
        cjv[2] = bflo(cjp.y); cjv[3] = bfhi(cjp.y);
        cjv[4] = bflo(cjp.z); cjv[5] = bfhi(cjp.z);
        cjv[6] = bflo(cjp.w); cjv[7] = bfhi(cjp.w);
        float4 wA[5], wB[5];              // w2 for this octet (broadcast)
        #pragma unroll
        for (int k = 0; k < 5; ++k) {
            wA[k] = *(const float4*)&w2t[k][w8 * 8];
            wB[k] = *(const float4*)&w2t[k][w8 * 8 + 4];
        }
        #pragma unroll
        for (int r = 0; r < 8; ++r) {
            uint4 aip = *(const uint4*)&ap[i0 + r][w8 * 4];  // uniform bcast
            uint4 cip = *(const uint4*)&cp[i0 + r][w8 * 4];
            float s[8];
            s[0] = fmaxf(bflo(aip.x) + cjv[0], 0.f) + fmaxf(ajv[0] + bflo(cip.x), 0.f);
            s[1] = fmaxf(bfhi(aip.x) + cjv[1], 0.f) + fmaxf(ajv[1] + bfhi(cip.x), 0.f);
            s[2] = fmaxf(bflo(aip.y) + cjv[2], 0.f) + fmaxf(ajv[2] + bflo(cip.y), 0.f);
            s[3] = fmaxf(bfhi(aip.y) + cjv[3], 0.f) + fmaxf(ajv[3] + bfhi(cip.y), 0.f);
            s[4] = fmaxf(bflo(aip.z) + cjv[4], 0.f) + fmaxf(ajv[4] + bflo(cip.z), 0.f);
            s[5] = fmaxf(bfhi(aip.z) + cjv[5], 0.f) + fmaxf(ajv[5] + bfhi(cip.z), 0.f);
            s[6] = fmaxf(bflo(aip.w) + cjv[6], 0.f) + fmaxf(ajv[6] + bflo(cip.w), 0.f);
            s[7] = fmaxf(bfhi(aip.w) + cjv[7], 0.f) + fmaxf(ajv[7] + bfhi(cip.w), 0.f);
            #pragma unroll
            for (int k = 0; k < 5; ++k) {
                acc[r][k] += s[0] * wA[k].x + s[1] * wA[k].y +
                             s[2] * wA[k].z + s[3] * wA[k].w +
                             s[4] * wB[k].x + s[5] * wB[k].y +
                             s[6] * wB[k].z + s[7] * wB[k].w;
            }
        }
    }

    #pragma unroll
    for (int r = 0; r < 8; ++r) {
        const int i = i0 + r;
        float* op = out + ((size_t)(b * 64 + i) * 64 + j) * 5;
        if (i >= n) {
            #pragma unroll
            for (int k = 0; k < 5; ++k) op[k] = fillv[k];
        } else {
            const bool masked = (j == i) || (j >= n);
            #pragma unroll
            for (int k = 0; k < 5; ++k)
                op[k] = masked ? fillv[k] : (0.5f * acc[r][k] + b2v[k]);
        }
    }
}

extern "C" void kernel_launch(void* const* d_in, const int* in_sizes, int n_in,
                              void* d_out, int out_size, void* d_ws, size_t ws_size,
                              hipStream_t stream)
{
    const float* z  = (const float*)d_in[0];   // (256, 256) fp32
    const int*   nra = (const int*)d_in[1];    // (256,) int32
    const float* Wn = (const float*)d_in[2];   // (256, 4096) fp32
    const float* bn = (const float*)d_in[3];   // (4096,) fp32
    const float* W1 = (const float*)d_in[4];   // (128, 64) fp32
    const float* b1 = (const float*)d_in[5];   // (64,) fp32
    const float* W2 = (const float*)d_in[6];   // (64, 5) fp32
    const float* b2 = (const float*)d_in[7];   // (5,) fp32
    float* out = (float*)d_out;                // (256, 64, 64, 5) fp32

    bf16* a_ws = (bf16*)d_ws;                  // 256*4096 bf16 (a' = a + b1)
    bf16* c_ws = a_ws + 256 * 4096;            // 256*4096 bf16

    hipLaunchKernelGGL(k_hac, dim3(64, 4), dim3(256), 0, stream,
                       z, Wn, bn, W1, b1, a_ws, c_ws);
    hipLaunchKernelGGL(k_pairs, dim3(512), dim3(256), 0, stream,
                       a_ws, c_ws, nra, W2, b2, out);
}

// Round 7
// 100.942 us; speedup vs baseline: 1.1733x; 1.0901x over previous
//
#include <hip/hip_runtime.h>
#include <hip/hip_bf16.h>

// Problem constants: B=256, LATENT=256, N=64, EMB=64, NBOND=5
// Dtypes (established R2-R4): ALL float tensors fp32 (inputs AND output),
// nra int32. Threshold 20.0 -> bf16 internals are free precision-wise.
// Timing note (R6): ~95-100 us of dur_us is fixed harness overhead
// (0xAA re-poison of 256 MiB d_ws at ~41.4 us + d_out fill + restores);
// our two kernels are ~10 us combined.
#define HUGEF 1000.0f

typedef __hip_bfloat16 bf16;
typedef __attribute__((ext_vector_type(8))) short short8;   // MFMA A/B frag (8 bf16)
typedef __attribute__((ext_vector_type(4))) float floatx4;  // MFMA C/D frag
typedef __attribute__((ext_vector_type(2))) float float2v;  // v_pk_* pair

__device__ __forceinline__ ushort f2bf(float x) {
    return __bfloat16_as_ushort(__float2bfloat16(x));
}
__device__ __forceinline__ float b2f(bf16 x) { return __bfloat162float(x); }
__device__ __forceinline__ float2v relu2(float2v x) {
    float2v r; r.x = fmaxf(x.x, 0.f); r.y = fmaxf(x.y, 0.f); return r;
}
__device__ __forceinline__ float2v mk2(float x, float y) {
    float2v r; r.x = x; r.y = y; return r;
}

// -------------------------------------------------------------------------
// Kernel 1 (R6, unchanged — known good):
//   h = z@Wn + bn ; a' = h@W1a + b1 ; c = h@W1b   (full MFMA, bf16 internals)
// -------------------------------------------------------------------------
__global__ __launch_bounds__(256) void k_hac(
    const float* __restrict__ z, const float* __restrict__ Wn,
    const float* __restrict__ bn, const float* __restrict__ W1,
    const float* __restrict__ b1, bf16* __restrict__ a_ws,
    bf16* __restrict__ c_ws)
{
    __shared__ ushort zt[64][136];   // z-tile  [m][k0..127] bf16
    __shared__ ushort wnt[64][136];  // Wn-tile [n][k0..127] bf16
    __shared__ ushort ht[64][72];    // h       [m][e] bf16
    __shared__ ushort w1at[64][72];  // W1a^T   [f][e] bf16
    __shared__ ushort w1bt[64][72];  // W1b^T   [f][e] bf16

    const int t = threadIdx.x;
    const int lane = t & 63;
    const int wv = t >> 6;
    const int l15 = lane & 15;
    const int quad = lane >> 4;
    const int atom = blockIdx.x;
    const int m0 = blockIdx.y * 64;
    const int n0 = atom * 64;

    {   // stage W1a/W1b transposed
        const int f = t & 63;
        const int g = t >> 6;
        #pragma unroll
        for (int qq = 0; qq < 4; ++qq) {
            int e = g * 16 + qq * 4;
            ushort4 va, vb;
            va.x = f2bf(W1[(e + 0) * 64 + f]);
            va.y = f2bf(W1[(e + 1) * 64 + f]);
            va.z = f2bf(W1[(e + 2) * 64 + f]);
            va.w = f2bf(W1[(e + 3) * 64 + f]);
            vb.x = f2bf(W1[(64 + e + 0) * 64 + f]);
            vb.y = f2bf(W1[(64 + e + 1) * 64 + f]);
            vb.z = f2bf(W1[(64 + e + 2) * 64 + f]);
            vb.w = f2bf(W1[(64 + e + 3) * 64 + f]);
            *(ushort4*)&w1at[f][e] = va;
            *(ushort4*)&w1bt[f][e] = vb;
        }
    }

    floatx4 acc1[4] = {};
    for (int kt = 0; kt < 256; kt += 128) {
        __syncthreads();
        #pragma unroll
        for (int r = 0; r < 8; ++r) {             // zt <- z (coalesced f4)
            int q = t + 256 * r;
            int m = q >> 5, kk = (q & 31) * 4;
            float4 v = *(const float4*)&z[(m0 + m) * 256 + kt + kk];
            ushort4 u = {f2bf(v.x), f2bf(v.y), f2bf(v.z), f2bf(v.w)};
            *(ushort4*)&zt[m][kk] = u;
        }
        {                                          // wnt[n][k] <- Wn^T gather
            int n = t & 63, g = t >> 6;
            #pragma unroll
            for (int qq = 0; qq < 8; ++qq) {
                int k = g * 32 + qq * 4;
                const float* p = &Wn[(size_t)(kt + k) * 4096 + n0 + n];
                ushort4 u = {f2bf(p[0]), f2bf(p[4096]),
                             f2bf(p[2 * 4096]), f2bf(p[3 * 4096])};
                *(ushort4*)&wnt[n][k] = u;
            }
        }
        __syncthreads();
        #pragma unroll
        for (int ks = 0; ks < 4; ++ks) {
            short8 a = *(const short8*)&zt[wv * 16 + l15][ks * 32 + quad * 8];
            #pragma unroll
            for (int nt = 0; nt < 4; ++nt) {
                short8 bf = *(const short8*)&wnt[nt * 16 + l15][ks * 32 + quad * 8];
                acc1[nt] = __builtin_amdgcn_mfma_f32_16x16x32_bf16(a, bf, acc1[nt], 0, 0, 0);
            }
        }
    }

    #pragma unroll
    for (int nt = 0; nt < 4; ++nt) {              // h (+bn) -> ht [m][e]
        float bnv = bn[n0 + nt * 16 + l15];
        #pragma unroll
        for (int r = 0; r < 4; ++r)
            ht[wv * 16 + quad * 4 + r][nt * 16 + l15] = f2bf(acc1[nt][r] + bnv);
    }
    __syncthreads();

    floatx4 acc2a[4] = {}, acc2c[4] = {};
    #pragma unroll
    for (int ks = 0; ks < 2; ++ks) {
        short8 a = *(const short8*)&ht[wv * 16 + l15][ks * 32 + quad * 8];
        #pragma unroll
        for (int ft = 0; ft < 4; ++ft) {
            short8 ba = *(const short8*)&w1at[ft * 16 + l15][ks * 32 + quad * 8];
            short8 bb = *(const short8*)&w1bt[ft * 16 + l15][ks * 32 + quad * 8];
            acc2a[ft] = __builtin_amdgcn_mfma_f32_16x16x32_bf16(a, ba, acc2a[ft], 0, 0, 0);
            acc2c[ft] = __builtin_amdgcn_mfma_f32_16x16x32_bf16(a, bb, acc2c[ft], 0, 0, 0);
        }
    }

    #pragma unroll
    for (int ft = 0; ft < 4; ++ft) {
        float b1v = b1[ft * 16 + l15];
        #pragma unroll
        for (int r = 0; r < 4; ++r) {
            int m = wv * 16 + quad * 4 + r;
            size_t idx = (size_t)(m0 + m) * 4096 + n0 + ft * 16 + l15;
            a_ws[idx] = __float2bfloat16(acc2a[ft][r] + b1v);
            c_ws[idx] = __float2bfloat16(acc2c[ft][r]);
        }
    }
}

// -------------------------------------------------------------------------
// Kernel 2 (R7): pairwise relu + W2 contraction + mask + symmetrize.
// VALU is the binding pipe (R6 post-mortem) -> fp32 LDS (no unpacks) and
// float2 packed math (v_pk_add_f32 / v_pk_fma_f32). Wave owns 8 rows.
// -------------------------------------------------------------------------
__global__ __launch_bounds__(256) void k_pairs(
    const bf16* __restrict__ a_ws, const bf16* __restrict__ c_ws,
    const int* __restrict__ nra, const float* __restrict__ W2,
    const float* __restrict__ b2, float* __restrict__ out)
{
    __shared__ __align__(16) float as[64][68];
    __shared__ __align__(16) float cs[64][68];
    __shared__ __align__(16) float w2t[5][68];

    const int t = threadIdx.x;
    const int b = blockIdx.x >> 1;
    const int ic = blockIdx.x & 1;
    const int n = nra[b];

    #pragma unroll
    for (int r = 0; r < 4; ++r) {                 // bf16 ws -> fp32 LDS
        int q = t + 256 * r;
        int atom = q >> 4, ff = (q & 15) * 4;
        ushort4 av = *(const ushort4*)((const ushort*)a_ws + (size_t)b * 4096 + 4 * q);
        ushort4 cv = *(const ushort4*)((const ushort*)c_ws + (size_t)b * 4096 + 4 * q);
        as[atom][ff + 0] = b2f(__ushort_as_bfloat16(av.x));
        as[atom][ff + 1] = b2f(__ushort_as_bfloat16(av.y));
        as[atom][ff + 2] = b2f(__ushort_as_bfloat16(av.z));
        as[atom][ff + 3] = b2f(__ushort_as_bfloat16(av.w));
        cs[atom][ff + 0] = b2f(__ushort_as_bfloat16(cv.x));
        cs[atom][ff + 1] = b2f(__ushort_as_bfloat16(cv.y));
        cs[atom][ff + 2] = b2f(__ushort_as_bfloat16(cv.z));
        cs[atom][ff + 3] = b2f(__ushort_as_bfloat16(cv.w));
    }
    if (t < 64) {
        #pragma unroll
        for (int k = 0; k < 5; ++k) w2t[k][t] = W2[t * 5 + k];
    }
    float b2v[5];
    #pragma unroll
    for (int k = 0; k < 5; ++k) b2v[k] = b2[k];
    __syncthreads();

    const int j = t & 63;
    const int wv = t >> 6;
    const int i0 = ic * 32 + wv * 8;              // this wave's 8 rows
    const float fillv[5] = {-HUGEF, -HUGEF, -HUGEF, -HUGEF, HUGEF};

    if (i0 >= n) {                                 // all 8 rows padding
        #pragma unroll
        for (int r = 0; r < 8; ++r) {
            float* op = out + ((size_t)(b * 64 + i0 + r) * 64 + j) * 5;
            #pragma unroll
            for (int k = 0; k < 5; ++k) op[k] = fillv[k];
        }
        return;
    }

    float2v acc2[8][5] = {};                       // pairwise accumulators
    for (int w8 = 0; w8 < 8; ++w8) {               // 8 f per iter
        const int f0 = w8 * 8;
        float4 ajA = *(const float4*)&as[j][f0];
        float4 ajB = *(const float4*)&as[j][f0 + 4];
        float4 cjA = *(const float4*)&cs[j][f0];
        float4 cjB = *(const float4*)&cs[j][f0 + 4];
        float2v aj0 = mk2(ajA.x, ajA.y), aj1 = mk2(ajA.z, ajA.w);
        float2v aj2 = mk2(ajB.x, ajB.y), aj3 = mk2(ajB.z, ajB.w);
        float2v cj0 = mk2(cjA.x, cjA.y), cj1 = mk2(cjA.z, cjA.w);
        float2v cj2 = mk2(cjB.x, cjB.y), cj3 = mk2(cjB.z, cjB.w);
        float2v w[5][4];
        #pragma unroll
        for (int k = 0; k < 5; ++k) {
            float4 wA = *(const float4*)&w2t[k][f0];
            float4 wB = *(const float4*)&w2t[k][f0 + 4];
            w[k][0] = mk2(wA.x, wA.y); w[k][1] = mk2(wA.z, wA.w);
            w[k][2] = mk2(wB.x, wB.y); w[k][3] = mk2(wB.z, wB.w);
        }
        #pragma unroll
        for (int r = 0; r < 8; ++r) {
            float4 aiA = *(const float4*)&as[i0 + r][f0];     // broadcast
            float4 aiB = *(const float4*)&as[i0 + r][f0 + 4];
            float4 ciA = *(const float4*)&cs[i0 + r][f0];
            float4 ciB = *(const float4*)&cs[i0 + r][f0 + 4];
            float2v s0 = relu2(mk2(aiA.x, aiA.y) + cj0) + relu2(aj0 + mk2(ciA.x, ciA.y));
            float2v s1 = relu2(mk2(aiA.z, aiA.w) + cj1) + relu2(aj1 + mk2(ciA.z, ciA.w));
            float2v s2 = relu2(mk2(aiB.x, aiB.y) + cj2) + relu2(aj2 + mk2(ciB.x, ciB.y));
            float2v s3 = relu2(mk2(aiB.z, aiB.w) + cj3) + relu2(aj3 + mk2(ciB.z, ciB.w));
            #pragma unroll
            for (int k = 0; k < 5; ++k)
                acc2[r][k] += s0 * w[k][0] + s1 * w[k][1] +
                              s2 * w[k][2] + s3 * w[k][3];
        }
    }

    #pragma unroll
    for (int r = 0; r < 8; ++r) {
        const int i = i0 + r;
        float* op = out + ((size_t)(b * 64 + i) * 64 + j) * 5;
        if (i >= n) {
            #pragma unroll
            for (int k = 0; k < 5; ++k) op[k] = fillv[k];
        } else {
            const bool masked = (j == i) || (j >= n);
            #pragma unroll
            for (int k = 0; k < 5; ++k) {
                float v = masked ? fillv[k]
                                 : (0.5f * (acc2[r][k].x + acc2[r][k].y) + b2v[k]);
                op[k] = v;
            }
        }
    }
}

extern "C" void kernel_launch(void* const* d_in, const int* in_sizes, int n_in,
                              void* d_out, int out_size, void* d_ws, size_t ws_size,
                              hipStream_t stream)
{
    const float* z  = (const float*)d_in[0];   // (256, 256) fp32
    const int*   nra = (const int*)d_in[1];    // (256,) int32
    const float* Wn = (const float*)d_in[2];   // (256, 4096) fp32
    const float* bn = (const float*)d_in[3];   // (4096,) fp32
    const float* W1 = (const float*)d_in[4];   // (128, 64) fp32
    const float* b1 = (const float*)d_in[5];   // (64,) fp32
    const float* W2 = (const float*)d_in[6];   // (64, 5) fp32
    const float* b2 = (const float*)d_in[7];   // (5,) fp32
    float* out = (float*)d_out;                // (256, 64, 64, 5) fp32

    bf16* a_ws = (bf16*)d_ws;                  // 256*4096 bf16 (a' = a + b1)
    bf16* c_ws = a_ws + 256 * 4096;            // 256*4096 bf16

    hipLaunchKernelGGL(k_hac, dim3(64, 4), dim3(256), 0, stream,
                       z, Wn, bn, W1, b1, a_ws, c_ws);
    hipLaunchKernelGGL(k_pairs, dim3(512), dim3(256), 0, stream,
                       a_ws, c_ws, nra, W2, b2, out);
}